// Round 15
// baseline (401.562 us; speedup 1.0000x reference)
//
#include <hip/hip_runtime.h>
#include <hip/hip_bf16.h>

#define BATCH 64
#define SEQ   256
#define EMB   64
#define QKVD  64
#define KD    8192      // L*EMB
#define ND    8192      // L*QKV
#define SEQD  16384     // SEQ*EMB (per-batch x row)
#define BKT   256       // k per tile: W row chunk = 1KB contiguous
#define NTK   (KD / BKT)   // 32 k-tiles

typedef __attribute__((ext_vector_type(8))) short bf16x8;
typedef __attribute__((ext_vector_type(4))) float f32x4;

struct WArgs { const float* W[6]; const float* b[6]; };

// branchless round-to-nearest-even fp32 -> bf16 bits (inputs are finite)
__device__ __forceinline__ short f2bf(float f) {
    unsigned u = __builtin_bit_cast(unsigned, f);
    u += 0x7fffu + ((u >> 16) & 1u);
    return (short)(u >> 16);
}

// async global->LDS, 16B per lane; LDS dest = wave-uniform base + lane*16
__device__ __forceinline__ void gl16(const void* g, void* l) {
    __builtin_amdgcn_global_load_lds(
        (const __attribute__((address_space(1))) void*)g,
        (__attribute__((address_space(3))) void*)l, 16, 0, 0);
}

__device__ __forceinline__ void barrier_fenced() {
    asm volatile("" ::: "memory");
    __builtin_amdgcn_s_barrier();
    asm volatile("" ::: "memory");
}

// ---------------- kernel 1: x fp32 -> bf16 ----------------------------------
__global__ __launch_bounds__(256)
void cvt_x_kernel(const float* __restrict__ x, short* __restrict__ xb) {
    const int i = (blockIdx.x * 256 + threadIdx.x) * 4;
    float4 v = *reinterpret_cast<const float4*>(x + i);
    short4 o;
    o.x = f2bf(v.x); o.y = f2bf(v.y); o.z = f2bf(v.z); o.w = f2bf(v.w);
    *reinterpret_cast<short4*>(xb + i) = o;
}

// ---------------- kernel 2: QKV projections ---------------------------------
// C[m][n] = sum_k xs[m,k] * W[n,k] + b[n], per gi in [0,6)
// Block = 32m x 32n, 4 waves (one 16x16 quadrant each: mq=wv&1, nq=wv>>1).
// LDS 80KB -> 2 blocks/CU: the co-resident block absorbs barrier stragglers
// (the r9 gap). W issues stay 1KB-contiguous; r9 counted-vmcnt ledger scaled:
//   prologue W(0)x8, A(0)x4, W(1)x8; loop: vmcnt(8) -> W(t),A(t) landed,
//   W(t+1) in flight; compute; barrier; stageA(t+1); stageW(t+2).
// M-split pairing: blocks (mh=0/1, same n,gi) land on the SAME XCD 8 dispatch
// slots apart -> co-resident, k-synced -> W panel's 2nd read is an L2 hit
// (HBM W traffic stays compulsory ~1.6GB; check = FETCH_SIZE unchanged).
__global__ __launch_bounds__(256, 2)
void qkv_gemm_kernel(const short* __restrict__ xb, WArgs wa,
                     float* __restrict__ qkv) {
    __shared__ __attribute__((aligned(16))) float W_lds[2][32 * BKT]; // 64KB
    __shared__ __attribute__((aligned(16))) short A_lds[32 * BKT];    // 16KB

    const int wv  = threadIdx.x >> 6;
    const int ln  = threadIdx.x & 63;
    const int r   = ln & 15;          // frag index (n for W/B, m for A)
    const int kb  = ln >> 4;          // k sub-block of 8 within 32
    const int key = r & 7;
    const int mq  = wv & 1;           // m quadrant
    const int nq  = wv >> 1;          // n quadrant

    // pairing swizzle: xcd = bid&7 owns pairids [xcd*192, +192); pair members
    // (mh=0,1) are 8 dispatch slots apart on the same XCD.
    const int bid = blockIdx.x;
    const int xcd = bid & 7;
    const int q   = bid >> 3;                  // 0..383
    const int mh  = q & 1;
    const int p   = xcd * 192 + (q >> 1);      // pairid 0..1535
    const int gi  = p >> 8;                    // 0..5
    const int n0  = (p & 255) * 32;            // n-tile origin
    const int g   = gi / 3;
    const int m0  = mh * 32;                   // m-half origin

    const char*  __restrict__ Wb8 =
        (const char*)(wa.W[gi] + (size_t)n0 * KD);
    const short* __restrict__ Ag = xb + g * KD;

    f32x4 acc = {0.f, 0.f, 0.f, 0.f};

    auto stageW = [&](int t, int slot) {       // 8 issues/wave, 1KB each
        const char* tb = Wb8 + (size_t)t * 1024;
        #pragma unroll
        for (int i = 0; i < 8; ++i) {
            const int row = wv * 8 + i;        // 0..31
            gl16(tb + (size_t)row * (KD * 4) + ((ln ^ (row & 7)) << 4),
                 (char*)&W_lds[slot][0] + row * 1024);
        }
    };
    auto stageA = [&](int t) {                 // 4 issues/wave (rows in pairs)
        #pragma unroll
        for (int j = 0; j < 4; ++j) {
            const int jj  = wv * 4 + j;        // 0..15, covers rows 2jj,2jj+1
            const int row = 2 * jj + (ln >> 5);
            const int c   = (ln & 31) ^ (row & 7);
            gl16((const char*)(Ag + (size_t)(m0 + row) * SEQD)
                     + (size_t)t * 512 + (c << 4),
                 (char*)&A_lds[0] + jj * 1024);
        }
    };

    auto compute = [&](int slot) {
        const float* Wrow = &W_lds[slot][0] + (nq * 16 + r) * BKT;
        const char*  Ab   = (const char*)&A_lds[0] + (mq * 16 + r) * 512;
        #pragma unroll
        for (int s = 0; s < 8; ++s) {
            const int cg = s * 8 + kb * 2;
            f32x4 w0 = *(const f32x4*)(Wrow + (((cg)     ^ key) << 2));
            f32x4 w1 = *(const f32x4*)(Wrow + (((cg + 1) ^ key) << 2));
            bf16x8 bb;
            bb[0] = f2bf(w0[0]); bb[1] = f2bf(w0[1]);
            bb[2] = f2bf(w0[2]); bb[3] = f2bf(w0[3]);
            bb[4] = f2bf(w1[0]); bb[5] = f2bf(w1[1]);
            bb[6] = f2bf(w1[2]); bb[7] = f2bf(w1[3]);
            const int ca = (s * 4 + kb) ^ key;  // A 16B-chunk (swizzled)
            const bf16x8 a = *(const bf16x8*)(Ab + (ca << 4));
            acc = __builtin_amdgcn_mfma_f32_16x16x32_bf16(a, bb, acc, 0, 0, 0);
        }
    };

    // prologue ledger: W(0)x8, A(0)x4, W(1)x8
    stageW(0, 0);
    stageA(0);
    stageW(1, 1);

    for (int t = 0; t < NTK; ++t) {
        if (t < NTK - 1) { asm volatile("s_waitcnt vmcnt(8)" ::: "memory"); }
        else             { asm volatile("s_waitcnt vmcnt(0)" ::: "memory"); }
        __builtin_amdgcn_sched_barrier(0);
        barrier_fenced();            // all waves' tile-t stages in LDS
        compute(t & 1);
        barrier_fenced();            // WAR: A buf + W slot free
        if (t + 1 < NTK) stageA(t + 1);
        if (t + 2 < NTK) stageW(t + 2, t & 1);
    }

    // D layout (m89): col = lane&15, row = (lane>>4)*4 + reg
    const int nbr = n0 + nq * 16 + r;
    const float bias = wa.b[gi][nbr];
    float* orow = qkv + (size_t)gi * (BATCH * ND) + nbr;
    #pragma unroll
    for (int reg = 0; reg < 4; ++reg) {
        const int m = m0 + mq * 16 + kb * 4 + reg;
        orow[(size_t)m * ND] = acc[reg] + bias;
    }
}

// ---------------- kernel 3: attention per (batch, group) -------------------
// scores[i][j] = Q[i,:]·K[j,:]; softmax over i (query axis); Z = attn·V; ×0.125
__global__ __launch_bounds__(256)
void attn_kernel(const float* __restrict__ qkv, float* __restrict__ out) {
    __shared__ float Ql[128 * 65];   // Q, then reused for V
    __shared__ float Kl[128 * 65];
    __shared__ float Sc[128 * 129];
    __shared__ float Pm[256];
    __shared__ float Ps[256];
    __shared__ float Rden[128];

    const int b = blockIdx.x;
    const int g = blockIdx.y;
    const int t = threadIdx.x;

    const float* __restrict__ Qg = qkv + ((size_t)(3 * g + 0) * BATCH + b) * ND;
    const float* __restrict__ Kg = qkv + ((size_t)(3 * g + 1) * BATCH + b) * ND;
    const float* __restrict__ Vg = qkv + ((size_t)(3 * g + 2) * BATCH + b) * ND;

    for (int e = t; e < 8192; e += 256) {
        const int i = e >> 6, k = e & 63;
        Ql[i * 65 + k] = Qg[e];
        Kl[i * 65 + k] = Kg[e];
    }
    __syncthreads();

    // scores: 8x8 register tile per thread
    {
        const int i0 = (t >> 4) * 8;
        const int j0 = (t & 15) * 8;
        float s[8][8];
        #pragma unroll
        for (int rr = 0; rr < 8; ++rr)
            #pragma unroll
            for (int cc = 0; cc < 8; ++cc) s[rr][cc] = 0.f;
        for (int k = 0; k < 64; ++k) {
            float qv[8], kv[8];
            #pragma unroll
            for (int rr = 0; rr < 8; ++rr) qv[rr] = Ql[(i0 + rr) * 65 + k];
            #pragma unroll
            for (int cc = 0; cc < 8; ++cc) kv[cc] = Kl[(j0 + cc) * 65 + k];
            #pragma unroll
            for (int rr = 0; rr < 8; ++rr)
                #pragma unroll
                for (int cc = 0; cc < 8; ++cc)
                    s[rr][cc] = fmaf(qv[rr], kv[cc], s[rr][cc]);
        }
        #pragma unroll
        for (int rr = 0; rr < 8; ++rr)
            #pragma unroll
            for (int cc = 0; cc < 8; ++cc)
                Sc[(i0 + rr) * 129 + (j0 + cc)] = s[rr][cc];
    }
    __syncthreads();

    // V fill (Q dead) + per-column partial max; column j, half h
    const int j = t & 127, h = t >> 7;
    {
        for (int e = t; e < 8192; e += 256) {
            const int i = e >> 6, k = e & 63;
            Ql[i * 65 + k] = Vg[e];
        }
        float m = -3.0e38f;
        for (int i = h * 64; i < h * 64 + 64; ++i)
            m = fmaxf(m, Sc[i * 129 + j]);
        Pm[h * 128 + j] = m;
    }
    __syncthreads();
    {
        const float m = fmaxf(Pm[j], Pm[128 + j]);
        float sum = 0.f;
        for (int i = h * 64; i < h * 64 + 64; ++i) {
            const float e = __expf(Sc[i * 129 + j] - m);
            Sc[i * 129 + j] = e;
            sum += e;
        }
        Ps[h * 128 + j] = sum;
    }
    __syncthreads();
    if (t < 128) Rden[t] = 1.0f / (Ps[t] + Ps[128 + t]);
    __syncthreads();

    // PV: 8 rows x 4 cols per thread
    {
        const int i0 = (t >> 4) * 8;
        const int k0 = (t & 15) * 4;
        float z[8][4];
        #pragma unroll
        for (int rr = 0; rr < 8; ++rr)
            #pragma unroll
            for (int cc = 0; cc < 4; ++cc) z[rr][cc] = 0.f;
        for (int jj = 0; jj < 128; ++jj) {
            const float rd = Rden[jj];
            float av[8], vv[4];
            #pragma unroll
            for (int rr = 0; rr < 8; ++rr) av[rr] = Sc[(i0 + rr) * 129 + jj] * rd;
            #pragma unroll
            for (int cc = 0; cc < 4; ++cc) vv[cc] = Ql[jj * 65 + k0 + cc];
            #pragma unroll
            for (int rr = 0; rr < 8; ++rr)
                #pragma unroll
                for (int cc = 0; cc < 4; ++cc)
                    z[rr][cc] = fmaf(av[rr], vv[cc], z[rr][cc]);
        }
        float* op = out + (size_t)b * (SEQ * QKVD) + (size_t)(g * 128) * QKVD + k0;
        #pragma unroll
        for (int rr = 0; rr < 8; ++rr) {
            float4 o;
            o.x = z[rr][0] * 0.125f; o.y = z[rr][1] * 0.125f;
            o.z = z[rr][2] * 0.125f; o.w = z[rr][3] * 0.125f;
            *reinterpret_cast<float4*>(op + (size_t)(i0 + rr) * QKVD) = o;
        }
    }
}

// ---------------- launcher --------------------------------------------------
extern "C" void kernel_launch(void* const* d_in, const int* in_sizes, int n_in,
                              void* d_out, int out_size, void* d_ws, size_t ws_size,
                              hipStream_t stream) {
    const float* x = (const float*)d_in[0];
    WArgs wa;
    for (int g = 0; g < 2; ++g)
        for (int q = 0; q < 3; ++q) {
            wa.W[g * 3 + q] = (const float*)d_in[1 + g * 6 + q * 2];
            wa.b[g * 3 + q] = (const float*)d_in[2 + g * 6 + q * 2];
        }

    short* xb  = (short*)d_ws;                                      // 2 MiB
    float* qkv = (float*)((char*)d_ws + (size_t)4 * 1024 * 1024);   // 12.6 MiB

    cvt_x_kernel<<<dim3(1024), dim3(256), 0, stream>>>(x, xb);
    qkv_gemm_kernel<<<dim3(3072), dim3(256), 0, stream>>>(xb, wa, qkv);
    attn_kernel<<<dim3(BATCH, 2), dim3(256), 0, stream>>>(qkv, (float*)d_out);
}